// Round 1
// baseline (19.671 us; speedup 1.0000x reference)
//
#include <hip/hip_runtime.h>

#define NB 1024   // batch
#define NS 128    // samples per qa
#define NL 256    // max question locs

// ---------------------------------------------------------------------------
// Mask-layout detection: the reference mask is jnp.bool_. Depending on the
// harness it may arrive as 1-byte bools or as int32 0/1. Distinguish them:
// scan the first NB*NL bytes (safe under both layouts) as u32; any nonzero
// byte at position %4 != 0 is impossible for little-endian int32 {0,1}
// values, but statistically certain for a random 0/1 byte mask.
// flag=1 -> u8 layout, flag=0 -> int32 layout.
// ---------------------------------------------------------------------------
__global__ void detect_mask_layout(const uint4* __restrict__ m, int* __restrict__ flag) {
    const int i = blockIdx.x * blockDim.x + threadIdx.x;   // i < NB*NL/16
    const uint4 v = m[i];
    const unsigned int acc = (v.x | v.y | v.z | v.w) & 0xFFFFFF00u;
    if (__any(acc != 0)) {
        if ((threadIdx.x & 63) == 0) atomicOr(flag, 1);
    }
}

// ---------------------------------------------------------------------------
// Main kernel: one block per batch element b, 256 threads.
// Phase 1: thread l precomputes sin/cos of question loc l (lat,lon) and the
//          mask penalty, staged in LDS (broadcast-read in phase 2).
// Phase 2: thread (s, half) accumulates min over half of L using the
//          haversine identity  sin^2(d/2) = 0.5 - 0.5*cos(d),
//          cos(d) = cA*cB + sA*sB  -> pure FMA inner loop.
//          asin(sqrt(.)) is monotone, so it is applied ONCE after the min.
//          Masked-out locs carry a +1e9 penalty folded into the 0.5 constant;
//          amin > 1e8 means the whole row was masked -> fill 2.0.
// ---------------------------------------------------------------------------
__global__ __launch_bounds__(256) void distance_encoder_kernel(
    const float* __restrict__ q,            // [NB, NL, 2]
    const unsigned char* __restrict__ mraw, // [NB, NL] bool (u8 or i32, see flag)
    const float* __restrict__ ent,          // [NB, NS, 2]
    float* __restrict__ out,                // [NB, NS]
    const int* __restrict__ flag)
{
    __shared__ float4 s_q[NL];    // (sin lat, cos lat, sin lon, cos lon)
    __shared__ float  s_pen[NL];  // 0.5 (valid) or 1e9 (masked out)
    __shared__ float  s_part[NS]; // partial mins from half 0

    const int b   = blockIdx.x;
    const int tid = threadIdx.x;
    const bool mask_is_u8 = (*flag != 0);   // uniform branch

    // Phase 1: one question loc per thread
    {
        const int l = tid;
        const float2 ql = reinterpret_cast<const float2*>(q)[b * NL + l];
        float sl, cl, so, co;
        sincosf(ql.x * 1.5707963267948966f, &sl, &cl);  // *90deg -> rad
        sincosf(ql.y * 3.1415926535897932f, &so, &co);  // *180deg -> rad
        s_q[l] = make_float4(sl, cl, so, co);
        const int mk = mask_is_u8
                     ? (int)mraw[b * NL + l]
                     : reinterpret_cast<const int*>(mraw)[b * NL + l];
        s_pen[l] = mk ? 0.5f : 1.0e9f;
    }

    // This thread's entity point
    const int s    = tid & (NS - 1);
    const int half = tid >> 7;   // 0 or 1: which half of L
    const float2 el = reinterpret_cast<const float2*>(ent)[b * NS + s];
    float sle, cle, soe, coe;
    sincosf(el.x * 1.5707963267948966f, &sle, &cle);
    sincosf(el.y * 3.1415926535897932f, &soe, &coe);

    __syncthreads();

    // Phase 2: FMA-only inner loop over this thread's half of L
    float amin = 1.0e30f;
    const int l0 = half * (NL / 2);
    #pragma unroll 8
    for (int i = 0; i < NL / 2; ++i) {
        const int l = l0 + i;
        const float4 qq = s_q[l];                      // broadcast ds_read_b128
        const float p       = cle * qq.y;              // cos(elat)*cos(qlat) >= 0
        const float cosdlat = fmaf(sle, qq.x, p);
        const float cosdlon = fmaf(soe, qq.z, coe * qq.w);
        const float u = fmaf(-0.5f, cosdlat, s_pen[l]); // sin^2(dlat/2) (+pen)
        const float v = fmaf(-0.5f, cosdlon, 0.5f);     // sin^2(dlon/2)
        const float a = fmaf(p, v, u);
        amin = fminf(amin, a);
    }

    // Combine halves, finish with a single asin(sqrt(.))
    if (half == 0) s_part[s] = amin;
    __syncthreads();
    if (half == 1) {
        amin = fminf(amin, s_part[s]);
        const float dis = (amin > 1.0e8f)
                        ? 2.0f
                        : asinf(sqrtf(fminf(fmaxf(amin, 0.0f), 1.0f)));
        out[b * NS + s] = -dis;
    }
}

extern "C" void kernel_launch(void* const* d_in, const int* in_sizes, int n_in,
                              void* d_out, int out_size, void* d_ws, size_t ws_size,
                              hipStream_t stream) {
    const float* q             = (const float*)d_in[0];
    const unsigned char* mraw  = (const unsigned char*)d_in[1];
    const float* ent           = (const float*)d_in[2];
    float* out                 = (float*)d_out;
    int* flag                  = (int*)d_ws;

    hipMemsetAsync(flag, 0, sizeof(int), stream);  // graph-capture legal
    detect_mask_layout<<<(NB * NL / 16) / 256, 256, 0, stream>>>(
        (const uint4*)mraw, flag);
    distance_encoder_kernel<<<NB, 256, 0, stream>>>(q, mraw, ent, out, flag);
}

// Round 2
// 11.526 us; speedup vs baseline: 1.7068x; 1.7068x over previous
//
#include <hip/hip_runtime.h>

#define NB 1024   // batch
#define NS 128    // samples per qa
#define NL 256    // max question locs

// ---------------------------------------------------------------------------
// Single-dispatch distance encoder. One block per batch element b, 256 threads.
//
// Mask-layout note: the reference mask is jnp.bool_ and may arrive as 1-byte
// bools or int32 0/1. Block-local detection: bytes [b*256, b*256+256) are
// in-bounds under BOTH layouts (u8 buffer = 256KB, i32 buffer = 1MB). Any
// nonzero byte at offset %4 != 0 is impossible for little-endian i32 {0,1}
// but near-certain for a random 0/1 byte row (P(miss) = 2^-192) -> u8.
//
// Math: with E=(entity lat,lon rad), Q=(question lat,lon rad),
//   a = sin^2(dlat/2) + cosE*cosQ*sin^2(dlon/2)
//     = 0.5 - 0.5*cos(dlat) + cosE*cosQ*(0.5 - 0.5*cos(dlon))
// and the +-0.5*cosE*cosQ terms cancel, leaving
//   a = pen + k1*sQ + k2*(cQ*sinLQ) + k3*(cQ*cosLQ)
// with k1=-0.5*sinE, k2=-0.5*cosE*sinLE, k3=-0.5*cosE*cosLE and pen=0.5 for
// valid locs, 1e9 for masked ones (monotone asin(sqrt(.)) applied ONCE after
// the min; amin>1e8 means all-masked row -> fill 2.0).
// Inner loop: 3 FMA + 1 fmin + 1 broadcast ds_read_b128 per location.
// ---------------------------------------------------------------------------
__global__ __launch_bounds__(256) void distance_encoder_kernel(
    const float* __restrict__ q,            // [NB, NL, 2]
    const unsigned char* __restrict__ mraw, // [NB, NL] bool (u8 or i32)
    const float* __restrict__ ent,          // [NB, NS, 2]
    float* __restrict__ out)                // [NB, NS]
{
    __shared__ float4       s_q[NL];       // (sQ, cQ*sinLQ, cQ*cosLQ, pen)
    __shared__ unsigned int s_mrow[NL/4];  // u8-candidate mask row
    __shared__ float        s_part[NS];    // partial mins from half 0
    __shared__ int          s_u8;

    const int b   = blockIdx.x;
    const int tid = threadIdx.x;

    // Early global loads (independent of detection)
    const float2 ql = reinterpret_cast<const float2*>(q)[b * NL + tid];
    const int    s  = tid & (NS - 1);
    const float2 el = reinterpret_cast<const float2*>(ent)[b * NS + s];

    // Phase 0: mask-layout detection on this block's u8-candidate row (wave 0)
    if (tid < 64) {
        const unsigned int w =
            reinterpret_cast<const unsigned int*>(mraw)[b * (NL / 4) + tid];
        s_mrow[tid] = w;
        const bool nz = (w & 0xFFFFFF00u) != 0;   // bytes at offset %4 != 0
        const unsigned long long bal = __ballot(nz);
        if (tid == 0) s_u8 = (bal != 0ull) ? 1 : 0;
    }
    __syncthreads();

    // Phase 1: one question loc per thread -> LDS tuple
    {
        float sl, cl, so, co;
        sincosf(ql.x * 1.5707963267948966f, &sl, &cl);  // *90deg -> rad
        sincosf(ql.y * 3.1415926535897932f, &so, &co);  // *180deg -> rad
        int mk;
        if (s_u8) {                                     // uniform branch
            mk = (s_mrow[tid >> 2] >> ((tid & 3) * 8)) & 0xFF;
        } else {
            mk = reinterpret_cast<const int*>(mraw)[b * NL + tid];
        }
        s_q[tid] = make_float4(sl, cl * so, cl * co, mk ? 0.5f : 1.0e9f);
    }

    // Per-thread entity constants
    float sle, cle, soe, coe;
    sincosf(el.x * 1.5707963267948966f, &sle, &cle);
    sincosf(el.y * 3.1415926535897932f, &soe, &coe);
    const float k1 = -0.5f * sle;
    const float k2 = -0.5f * cle * soe;
    const float k3 = -0.5f * cle * coe;

    __syncthreads();

    // Phase 2: 3-FMA inner loop over this thread's half of L, 2 accumulators
    const int half = tid >> 7;               // 0 or 1
    const int l0   = half * (NL / 2);
    float amin0 = 1.0e30f, amin1 = 1.0e30f;
    #pragma unroll 8
    for (int i = 0; i < NL / 2; i += 2) {
        const float4 qa = s_q[l0 + i];        // broadcast ds_read_b128
        const float4 qb = s_q[l0 + i + 1];
        float a0 = fmaf(k1, qa.x, qa.w);
        a0 = fmaf(k2, qa.y, a0);
        a0 = fmaf(k3, qa.z, a0);
        float a1 = fmaf(k1, qb.x, qb.w);
        a1 = fmaf(k2, qb.y, a1);
        a1 = fmaf(k3, qb.z, a1);
        amin0 = fminf(amin0, a0);
        amin1 = fminf(amin1, a1);
    }
    float amin = fminf(amin0, amin1);

    // Combine halves, single asin(sqrt(.)) per output
    if (half == 0) s_part[s] = amin;
    __syncthreads();
    if (half == 1) {
        amin = fminf(amin, s_part[s]);
        const float dis = (amin > 1.0e8f)
                        ? 2.0f
                        : asinf(sqrtf(fminf(fmaxf(amin, 0.0f), 1.0f)));
        out[b * NS + s] = -dis;
    }
}

extern "C" void kernel_launch(void* const* d_in, const int* in_sizes, int n_in,
                              void* d_out, int out_size, void* d_ws, size_t ws_size,
                              hipStream_t stream) {
    const float* q            = (const float*)d_in[0];
    const unsigned char* mraw = (const unsigned char*)d_in[1];
    const float* ent          = (const float*)d_in[2];
    float* out                = (float*)d_out;

    distance_encoder_kernel<<<NB, 256, 0, stream>>>(q, mraw, ent, out);
}

// Round 3
// 10.429 us; speedup vs baseline: 1.8862x; 1.1051x over previous
//
#include <hip/hip_runtime.h>

#define NB 1024   // batch
#define NS 128    // samples per qa
#define NL 256    // max question locs

// ---------------------------------------------------------------------------
// Single-dispatch distance encoder. One block per batch element b, 256 threads
// (4 waves). Math (see R1/R2): per (entity s, loc l),
//   a = pen_l + k1_s*x_l + k2_s*y_l + k3_s*z_l        (3 FMA + 1 min)
// with q-tuple (x,y,z,pen) and entity k-tuple staged in LDS once per block.
// asin(sqrt(.)) is monotone -> applied once per output after the min.
// pen = 0.5 valid / 1e9 masked; amin > 1e8 => all-masked row -> fill 2.0.
//
// Work decomposition: lane sb = lane&31 owns 4 s-slots {sb,+32,+64,+96};
// (wave, lane-half) picks one of 8 l-chunks of 32 locs. One broadcast
// ds_read_b128 feeds 16 VALU ops (4 s-slots x 4 ops) -> DS pressure 4x lower
// than one-s-per-thread. Per-wave DS reads use 2 addresses (free, m136).
//
// Trig: native v_sin_f32/v_cos_f32 via __builtin_amdgcn_{sinf,cosf}, which
// take REVOLUTIONS (D = sin(S0*2pi)): lat*90deg -> x*0.25 rev, lon*180deg ->
// x*0.5 rev. One trans instr each vs ~30-instr libm sincosf.
//
// Mask layout (jnp.bool_ may be u8 or i32): block-local detection on bytes
// [b*256, b*256+256) — in-bounds under BOTH layouts; any nonzero byte at
// offset %4 != 0 is impossible for little-endian i32 {0,1}.
// ---------------------------------------------------------------------------
__global__ __launch_bounds__(256) void distance_encoder_kernel(
    const float* __restrict__ q,            // [NB, NL, 2]
    const unsigned char* __restrict__ mraw, // [NB, NL] bool (u8 or i32)
    const float* __restrict__ ent,          // [NB, NS, 2]
    float* __restrict__ out)                // [NB, NS]
{
    __shared__ float4       s_q[NL];        // (x, y, z, pen)
    __shared__ float4       s_k[NS];        // (k1, k2, k3, 0)
    __shared__ float        s_part[8][NS];  // per-chunk partial mins
    __shared__ unsigned int s_mrow[NL/4];
    __shared__ int          s_u8;

    const int b    = blockIdx.x;
    const int tid  = threadIdx.x;
    const int lane = tid & 63;
    const int w    = tid >> 6;       // wave 0..3
    const int lh   = lane >> 5;      // lane half 0/1
    const int sb   = lane & 31;      // s base
    const int chunk = w * 2 + lh;    // l-chunk 0..7

    // Early global loads
    const float2 ql = reinterpret_cast<const float2*>(q)[b * NL + tid];
    float2 el;
    if (tid < NS) el = reinterpret_cast<const float2*>(ent)[b * NS + tid];

    // Phase 0: mask-layout detection (wave 0)
    if (tid < 64) {
        const unsigned int wd =
            reinterpret_cast<const unsigned int*>(mraw)[b * (NL / 4) + tid];
        s_mrow[tid] = wd;
        const unsigned long long bal = __ballot((wd & 0xFFFFFF00u) != 0);
        if (tid == 0) s_u8 = (bal != 0ull) ? 1 : 0;
    }
    __syncthreads();

    // Phase 1: stage q-tuples (all 256 threads) and k-tuples (first 128)
    {
        const float sl = __builtin_amdgcn_sinf(ql.x * 0.25f);  // sin(lat)
        const float cl = __builtin_amdgcn_cosf(ql.x * 0.25f);  // cos(lat)
        const float so = __builtin_amdgcn_sinf(ql.y * 0.5f);   // sin(lon)
        const float co = __builtin_amdgcn_cosf(ql.y * 0.5f);   // cos(lon)
        int mk;
        if (s_u8) mk = (s_mrow[tid >> 2] >> ((tid & 3) * 8)) & 0xFF;  // uniform branch
        else      mk = reinterpret_cast<const int*>(mraw)[b * NL + tid];
        s_q[tid] = make_float4(sl, cl * so, cl * co, mk ? 0.5f : 1.0e9f);
    }
    if (tid < NS) {
        const float sle = __builtin_amdgcn_sinf(el.x * 0.25f);
        const float cle = __builtin_amdgcn_cosf(el.x * 0.25f);
        const float soe = __builtin_amdgcn_sinf(el.y * 0.5f);
        const float coe = __builtin_amdgcn_cosf(el.y * 0.5f);
        s_k[tid] = make_float4(-0.5f * sle, -0.5f * cle * soe,
                               -0.5f * cle * coe, 0.0f);
    }
    __syncthreads();

    // Per-thread entity constants: 4 s-slots (2-way LDS reads, conflict-free)
    const float4 k0 = s_k[sb];
    const float4 k1 = s_k[sb + 32];
    const float4 k2 = s_k[sb + 64];
    const float4 k3 = s_k[sb + 96];

    // Phase 2: 32 iters, 1 broadcast ds_read_b128 : 16 VALU
    float m0 = 1e30f, m1 = 1e30f, m2 = 1e30f, m3 = 1e30f;
    const int l0 = chunk * 32;
    #pragma unroll 8
    for (int i = 0; i < 32; ++i) {
        const float4 qq = s_q[l0 + i];
        float a0 = fmaf(k0.x, qq.x, qq.w);
        float a1 = fmaf(k1.x, qq.x, qq.w);
        float a2 = fmaf(k2.x, qq.x, qq.w);
        float a3 = fmaf(k3.x, qq.x, qq.w);
        a0 = fmaf(k0.y, qq.y, a0);  a0 = fmaf(k0.z, qq.z, a0);
        a1 = fmaf(k1.y, qq.y, a1);  a1 = fmaf(k1.z, qq.z, a1);
        a2 = fmaf(k2.y, qq.y, a2);  a2 = fmaf(k2.z, qq.z, a2);
        a3 = fmaf(k3.y, qq.y, a3);  a3 = fmaf(k3.z, qq.z, a3);
        m0 = fminf(m0, a0);  m1 = fminf(m1, a1);
        m2 = fminf(m2, a2);  m3 = fminf(m3, a3);
    }
    // Partial-min write: banks = sb for all lanes -> 2-way (free)
    s_part[chunk][sb]      = m0;
    s_part[chunk][sb + 32] = m1;
    s_part[chunk][sb + 64] = m2;
    s_part[chunk][sb + 96] = m3;
    __syncthreads();

    // Phase 3: combine 8 chunks, single asin(sqrt(.)), coalesced store
    if (tid < NS) {
        float mm = s_part[0][tid];
        #pragma unroll
        for (int c = 1; c < 8; ++c) mm = fminf(mm, s_part[c][tid]);
        const float dis = (mm > 1.0e8f)
                        ? 2.0f
                        : asinf(sqrtf(fminf(fmaxf(mm, 0.0f), 1.0f)));
        out[b * NS + tid] = -dis;
    }
}

extern "C" void kernel_launch(void* const* d_in, const int* in_sizes, int n_in,
                              void* d_out, int out_size, void* d_ws, size_t ws_size,
                              hipStream_t stream) {
    const float* q            = (const float*)d_in[0];
    const unsigned char* mraw = (const unsigned char*)d_in[1];
    const float* ent          = (const float*)d_in[2];
    float* out                = (float*)d_out;

    distance_encoder_kernel<<<NB, 256, 0, stream>>>(q, mraw, ent, out);
}

// Round 4
// 10.080 us; speedup vs baseline: 1.9516x; 1.0346x over previous
//
#include <hip/hip_runtime.h>

#define NB 1024   // batch
#define NS 128    // samples per qa
#define NL 256    // max question locs

// ---------------------------------------------------------------------------
// Single-dispatch distance encoder. One block per batch element b, 256 threads
// (4 waves). Math: per (entity s, loc l),
//   a = pen_l + k1_s*x_l + k2_s*y_l + k3_s*z_l        (3 FMA, min via min3)
// q-tuple (x,y,z,pen) and entity k-tuple staged in LDS once per block.
// asin(sqrt(.)) is monotone -> applied once per output after the min.
// pen = 0.5 valid / 1e9 masked; amin > 1e8 => all-masked row -> fill 2.0.
//
// Work decomposition: lane owns 8 s-slots {sb+16j}, sb = lane&15; the
// (wave, lane-group) pair picks one of 16 l-chunks of 16 locs. One broadcast
// ds_read_b128 feeds 28 VALU ops (8 s-slots) -> inner-loop DS instrs halved
// vs the 4-slot R3 layout (16/thread). l processed in pairs so the reduction
// is fminf(acc, fminf(a0,a1)) -> v_min3_f32 (0.5 min/pair).
//
// Trig: native v_sin_f32/v_cos_f32 (REVOLUTIONS: lat*90deg -> x*0.25 rev,
// lon*180deg -> x*0.5 rev). One trans instr vs ~30-instr libm sincosf.
//
// Mask layout (jnp.bool_ may be u8 or i32): block-local detection on bytes
// [b*256, b*256+256) — in-bounds under BOTH layouts; any nonzero byte at
// offset %4 != 0 is impossible for little-endian i32 {0,1}.
// ---------------------------------------------------------------------------
__global__ __launch_bounds__(256) void distance_encoder_kernel(
    const float* __restrict__ q,            // [NB, NL, 2]
    const unsigned char* __restrict__ mraw, // [NB, NL] bool (u8 or i32)
    const float* __restrict__ ent,          // [NB, NS, 2]
    float* __restrict__ out)                // [NB, NS]
{
    __shared__ float4       s_q[NL];          // (x, y, z, pen)
    __shared__ float4       s_k[NS];          // (k1, k2, k3, 0)
    __shared__ float        s_part[16][NS+1]; // per-chunk partial mins (padded)
    __shared__ unsigned int s_mrow[NL/4];
    __shared__ int          s_u8;

    const int b    = blockIdx.x;
    const int tid  = threadIdx.x;
    const int lane = tid & 63;
    const int w    = tid >> 6;        // wave 0..3
    const int sb   = lane & 15;       // s base (8 slots: sb + 16j)
    const int grp  = lane >> 4;       // lane group 0..3
    const int chunk = w * 4 + grp;    // l-chunk 0..15
    const int l0   = chunk * 16;

    // Early global loads
    const float2 ql = reinterpret_cast<const float2*>(q)[b * NL + tid];
    float2 el;
    if (tid < NS) el = reinterpret_cast<const float2*>(ent)[b * NS + tid];

    // Phase 0: mask-layout detection (wave 0)
    if (tid < 64) {
        const unsigned int wd =
            reinterpret_cast<const unsigned int*>(mraw)[b * (NL / 4) + tid];
        s_mrow[tid] = wd;
        const unsigned long long bal = __ballot((wd & 0xFFFFFF00u) != 0);
        if (tid == 0) s_u8 = (bal != 0ull) ? 1 : 0;
    }
    __syncthreads();

    // Phase 1: stage q-tuples (all 256 threads) and k-tuples (first 128)
    {
        const float sl = __builtin_amdgcn_sinf(ql.x * 0.25f);  // sin(lat)
        const float cl = __builtin_amdgcn_cosf(ql.x * 0.25f);  // cos(lat)
        const float so = __builtin_amdgcn_sinf(ql.y * 0.5f);   // sin(lon)
        const float co = __builtin_amdgcn_cosf(ql.y * 0.5f);   // cos(lon)
        int mk;
        if (s_u8) mk = (s_mrow[tid >> 2] >> ((tid & 3) * 8)) & 0xFF;  // uniform
        else      mk = reinterpret_cast<const int*>(mraw)[b * NL + tid];
        s_q[tid] = make_float4(sl, cl * so, cl * co, mk ? 0.5f : 1.0e9f);
    }
    if (tid < NS) {
        const float sle = __builtin_amdgcn_sinf(el.x * 0.25f);
        const float cle = __builtin_amdgcn_cosf(el.x * 0.25f);
        const float soe = __builtin_amdgcn_sinf(el.y * 0.5f);
        const float coe = __builtin_amdgcn_cosf(el.y * 0.5f);
        s_k[tid] = make_float4(-0.5f * sle, -0.5f * cle * soe,
                               -0.5f * cle * coe, 0.0f);
    }
    __syncthreads();

    // Per-thread entity constants: 8 s-slots
    float4 kk[8];
    #pragma unroll
    for (int j = 0; j < 8; ++j) kk[j] = s_k[sb + 16 * j];

    float acc[8];
    #pragma unroll
    for (int j = 0; j < 8; ++j) acc[j] = 1.0e30f;

    // Phase 2: 16 iters (paired), 1 broadcast ds_read_b128 : 28 VALU
    #pragma unroll
    for (int i = 0; i < 16; i += 2) {
        const float4 qa = s_q[l0 + i];
        const float4 qb = s_q[l0 + i + 1];
        #pragma unroll
        for (int j = 0; j < 8; ++j) {
            float a0 = fmaf(kk[j].x, qa.x, qa.w);
            a0 = fmaf(kk[j].y, qa.y, a0);
            a0 = fmaf(kk[j].z, qa.z, a0);
            float a1 = fmaf(kk[j].x, qb.x, qb.w);
            a1 = fmaf(kk[j].y, qb.y, a1);
            a1 = fmaf(kk[j].z, qb.z, a1);
            acc[j] = fminf(acc[j], fminf(a0, a1));   // -> v_min3_f32
        }
    }
    #pragma unroll
    for (int j = 0; j < 8; ++j) s_part[chunk][sb + 16 * j] = acc[j];
    __syncthreads();

    // Phase 3: combine 16 chunks, single asin(sqrt(.)), coalesced store
    if (tid < NS) {
        float mm = s_part[0][tid];
        #pragma unroll
        for (int c = 1; c < 16; ++c) mm = fminf(mm, s_part[c][tid]);
        const float dis = (mm > 1.0e8f)
                        ? 2.0f
                        : asinf(sqrtf(fminf(fmaxf(mm, 0.0f), 1.0f)));
        out[b * NS + tid] = -dis;
    }
}

extern "C" void kernel_launch(void* const* d_in, const int* in_sizes, int n_in,
                              void* d_out, int out_size, void* d_ws, size_t ws_size,
                              hipStream_t stream) {
    const float* q            = (const float*)d_in[0];
    const unsigned char* mraw = (const unsigned char*)d_in[1];
    const float* ent          = (const float*)d_in[2];
    float* out                = (float*)d_out;

    distance_encoder_kernel<<<NB, 256, 0, stream>>>(q, mraw, ent, out);
}

// Round 5
// 9.875 us; speedup vs baseline: 1.9921x; 1.0208x over previous
//
#include <hip/hip_runtime.h>

#define NB 1024   // batch
#define NS 128    // samples per qa
#define NL 256    // max question locs

// ---------------------------------------------------------------------------
// Single-dispatch distance encoder. One block per batch element b, 256 threads
// (4 waves), TWO barriers total. Math: per (entity s, loc l),
//   a = pen_l + k1_s*x_l + k2_s*y_l + k3_s*z_l        (3 FMA, min via min3)
// q-tuple (x,y,z,pen) and entity k-tuple staged in LDS once per block.
// asin(sqrt(.)) is monotone -> applied once per output after the min.
// pen = 0.5 valid / 1e9 masked; amin > 1e8 => all-masked row -> fill 2.0.
//
// Work decomposition: lane owns 8 s-slots {sb+16j}, sb = lane&15; the
// (wave, lane-group) pair picks one of 16 l-chunks of 16 locs. One broadcast
// ds_read_b128 feeds 28 VALU ops. l processed in pairs so the reduction is
// fminf(acc, fminf(a0,a1)) -> v_min3_f32. More s-slots/thread can't help:
// LDS cost = (128/slots) reads x (slots/2)-way divergence, plateaus >= 8.
//
// Mask layout (jnp.bool_ may be u8 or i32): each wave loads the WHOLE 64-word
// u8-candidate row (1 u32/lane, in-bounds under both layouts) and does an
// exact wave-local ballot: any nonzero byte at offset %4 != 0 is impossible
// for little-endian i32 {0,1} -> u8. Wave-uniform verdict, no LDS, no
// barrier; each thread pulls its loc's byte via one __shfl.
//
// Trig: native v_sin_f32/v_cos_f32 (REVOLUTIONS: lat*90deg -> x*0.25 rev,
// lon*180deg -> x*0.5 rev). One trans instr vs ~30-instr libm sincosf.
// ---------------------------------------------------------------------------
__global__ __launch_bounds__(256) void distance_encoder_kernel(
    const float* __restrict__ q,            // [NB, NL, 2]
    const unsigned char* __restrict__ mraw, // [NB, NL] bool (u8 or i32)
    const float* __restrict__ ent,          // [NB, NS, 2]
    float* __restrict__ out)                // [NB, NS]
{
    __shared__ float4 s_q[NL];          // (x, y, z, pen)
    __shared__ float4 s_k[NS];          // (k1, k2, k3, 0)
    __shared__ float  s_part[16][NS+1]; // per-chunk partial mins (padded)

    const int b    = blockIdx.x;
    const int tid  = threadIdx.x;
    const int lane = tid & 63;
    const int w    = tid >> 6;        // wave 0..3
    const int sb   = lane & 15;       // s base (8 slots: sb + 16j)
    const int grp  = lane >> 4;       // lane group 0..3
    const int chunk = w * 4 + grp;    // l-chunk 0..15
    const int l0   = chunk * 16;

    // --- Issue ALL global loads up front (overlap L2 latency with trig) ---
    const float2 ql = reinterpret_cast<const float2*>(q)[b * NL + tid];
    const unsigned int mw =
        reinterpret_cast<const unsigned int*>(mraw)[b * (NL / 4) + lane];
    float2 el;
    if (tid < NS) el = reinterpret_cast<const float2*>(ent)[b * NS + tid];

    // --- Wave-local, exact mask-layout detection (no LDS, no barrier) ---
    const bool u8 = __ballot((mw & 0xFFFFFF00u) != 0) != 0ull;  // wave-uniform
    int mk;
    if (u8) {   // my loc's byte lives in word tid>>2, held by lane tid>>2
        const unsigned int wword = __shfl(mw, tid >> 2);
        mk = (wword >> ((tid & 3) * 8)) & 0xFF;
    } else {    // i32 layout: in-bounds (1MB buffer), L2-hot
        mk = reinterpret_cast<const int*>(mraw)[b * NL + tid];
    }

    // --- Stage q-tuples (all 256 threads) and k-tuples (first 128) ---
    {
        const float sl = __builtin_amdgcn_sinf(ql.x * 0.25f);  // sin(lat)
        const float cl = __builtin_amdgcn_cosf(ql.x * 0.25f);  // cos(lat)
        const float so = __builtin_amdgcn_sinf(ql.y * 0.5f);   // sin(lon)
        const float co = __builtin_amdgcn_cosf(ql.y * 0.5f);   // cos(lon)
        s_q[tid] = make_float4(sl, cl * so, cl * co, mk ? 0.5f : 1.0e9f);
    }
    if (tid < NS) {
        const float sle = __builtin_amdgcn_sinf(el.x * 0.25f);
        const float cle = __builtin_amdgcn_cosf(el.x * 0.25f);
        const float soe = __builtin_amdgcn_sinf(el.y * 0.5f);
        const float coe = __builtin_amdgcn_cosf(el.y * 0.5f);
        s_k[tid] = make_float4(-0.5f * sle, -0.5f * cle * soe,
                               -0.5f * cle * coe, 0.0f);
    }
    __syncthreads();   // barrier 1 of 2

    // Per-thread entity constants: 8 s-slots
    float4 kk[8];
    #pragma unroll
    for (int j = 0; j < 8; ++j) kk[j] = s_k[sb + 16 * j];

    float acc[8];
    #pragma unroll
    for (int j = 0; j < 8; ++j) acc[j] = 1.0e30f;

    // Inner loop: 8 paired iters, 2 broadcast ds_read_b128 : 56 VALU
    #pragma unroll
    for (int i = 0; i < 16; i += 2) {
        const float4 qa = s_q[l0 + i];
        const float4 qb = s_q[l0 + i + 1];
        #pragma unroll
        for (int j = 0; j < 8; ++j) {
            float a0 = fmaf(kk[j].x, qa.x, qa.w);
            a0 = fmaf(kk[j].y, qa.y, a0);
            a0 = fmaf(kk[j].z, qa.z, a0);
            float a1 = fmaf(kk[j].x, qb.x, qb.w);
            a1 = fmaf(kk[j].y, qb.y, a1);
            a1 = fmaf(kk[j].z, qb.z, a1);
            acc[j] = fminf(acc[j], fminf(a0, a1));   // -> v_min3_f32
        }
    }
    #pragma unroll
    for (int j = 0; j < 8; ++j) s_part[chunk][sb + 16 * j] = acc[j];
    __syncthreads();   // barrier 2 of 2

    // Combine 16 chunks, single asin(sqrt(.)), coalesced store
    if (tid < NS) {
        float mm = s_part[0][tid];
        #pragma unroll
        for (int c = 1; c < 16; ++c) mm = fminf(mm, s_part[c][tid]);
        const float dis = (mm > 1.0e8f)
                        ? 2.0f
                        : asinf(sqrtf(fminf(fmaxf(mm, 0.0f), 1.0f)));
        out[b * NS + tid] = -dis;
    }
}

extern "C" void kernel_launch(void* const* d_in, const int* in_sizes, int n_in,
                              void* d_out, int out_size, void* d_ws, size_t ws_size,
                              hipStream_t stream) {
    const float* q            = (const float*)d_in[0];
    const unsigned char* mraw = (const unsigned char*)d_in[1];
    const float* ent          = (const float*)d_in[2];
    float* out                = (float*)d_out;

    distance_encoder_kernel<<<NB, 256, 0, stream>>>(q, mraw, ent, out);
}